// Round 12
// baseline (32.187 us; speedup 1.0000x reference)
//
#include <hip/hip_runtime.h>
#include <math.h>

// SparseMixer MoE routing: T tokens x 128 experts, top-2.
// R12: 16 lanes/token + 2-token ILP. R11 (8 lanes, 2 tokens) regressed
// 27.0->29.8: 32 data VGPR + temps > 64 under (256,8) => spill. Same ILP
// with HALF the data regs: 2 float4/token -> 16 data VGPR total, est ~50
// overall => true 8 waves/SIMD AND 2-deep load overlap per wave.
// Semantics identical to R8/R10/R11 (passed, absmax 0.002):
//   top-2 first-occurrence tie-break == ref {argmax; -inf; argmax}
//   masked <=> x < theta, theta = v>=0 ? 0.98v : v*(1/0.98)  [v>=x always]
//   s1 = sum_{x>=th1} exp(x-v1); s2 = (sum_{x>=th2} exp(x-v1) - 1)*exp(v1-v2)
// Output (floats): out[0..2T) = indices as float; out[2T..4T) = values.

#define NEXPERTS 128
#define INV098 1.0204082f

__device__ __forceinline__ void process_token(const float4 X0, const float4 X1,
                                              int sub, int token,
                                              float* __restrict__ out, int T)
{
    // Lane owns experts e = 4*sub + L, L = 64*c + j for chunk c in {0,1}.
    // Ascending (c,j) scan == ascending e => first-occurrence tie-break.
    float m1 = -INFINITY, m2 = -INFINITY;
    int   l1 = 0x7fffff, l2 = 0x7fffff;
    {
        const float xs0[4] = {X0.x, X0.y, X0.z, X0.w};
        #pragma unroll
        for (int j = 0; j < 4; ++j) {
            const float xv = xs0[j];
            if (xv > m1)      { m2 = m1; l2 = l1; m1 = xv; l1 = j; }
            else if (xv > m2) { m2 = xv; l2 = j; }
        }
        const float xs1[4] = {X1.x, X1.y, X1.z, X1.w};
        #pragma unroll
        for (int j = 0; j < 4; ++j) {
            const float xv = xs1[j];
            const int   L  = 64 + j;
            if (xv > m1)      { m2 = m1; l2 = l1; m1 = xv; l1 = L; }
            else if (xv > m2) { m2 = xv; l2 = L; }
        }
    }
    int i1 = 4 * sub + l1;   // global expert indices
    int i2 = 4 * sub + l2;

    // ---- 16-lane joint top-2 butterfly (offsets 8,4,2,1 stay in group).
    // Merge keeps {winner.top, best(winner.second, loser.top)}; ties -> smaller idx.
    #pragma unroll
    for (int off = 8; off > 0; off >>= 1) {
        float om1 = __shfl_xor(m1, off); int oi1 = __shfl_xor(i1, off);
        float om2 = __shfl_xor(m2, off); int oi2 = __shfl_xor(i2, off);
        float w1, ws, lt; int wi1, wis, lti;
        if (om1 > m1 || (om1 == m1 && oi1 < i1)) {
            w1 = om1; wi1 = oi1; ws = om2; wis = oi2; lt = m1;  lti = i1;
        } else {
            w1 = m1;  wi1 = i1;  ws = m2;  wis = i2;  lt = om1; lti = oi1;
        }
        if (lt > ws || (lt == ws && lti < wis)) { m2 = lt; i2 = lti; }
        else                                    { m2 = ws; i2 = wis; }
        m1 = w1; i1 = wi1;
    }
    const float v1 = m1, v2 = m2;

    // ---- theta thresholds: kept_s <=> x >= theta_s
    const float th1 = v1 * (v1 >= 0.f ? 0.98f : INV098);
    const float th2 = v2 * (v2 >= 0.f ? 0.98f : INV098);

    // ---- dual masked sums, one exp per element
    float s1 = 0.f, t2 = 0.f;
    {
        const float xs0[4] = {X0.x, X0.y, X0.z, X0.w};
        #pragma unroll
        for (int j = 0; j < 4; ++j) {
            const float xv = xs0[j];
            const float ev = __expf(xv - v1);
            if (xv >= th1) s1 += ev;
            if (xv >= th2) t2 += ev;
        }
        const float xs1[4] = {X1.x, X1.y, X1.z, X1.w};
        #pragma unroll
        for (int j = 0; j < 4; ++j) {
            const float xv = xs1[j];
            const float ev = __expf(xv - v1);
            if (xv >= th1) s1 += ev;
            if (xv >= th2) t2 += ev;   // includes i1's exp(0)=1
        }
    }
    // ---- 16-lane sum butterfly
    #pragma unroll
    for (int off = 8; off > 0; off >>= 1) {
        s1 += __shfl_xor(s1, off);
        t2 += __shfl_xor(t2, off);
    }

    if (sub == 0) {
        const float s2 = (t2 - 1.0f) * __expf(v1 - v2);  // remove i1, rescale
        out[(size_t)token * 2 + 0] = (float)i1;
        out[(size_t)token * 2 + 1] = (float)i2;
        float* vals = out + (size_t)2 * T;
        vals[(size_t)token * 2 + 0] = 1.0f / s1;
        vals[(size_t)token * 2 + 1] = 1.0f / s2;
    }
}

__global__ __launch_bounds__(256, 8) void sparsemixer_route_kernel(
    const float* __restrict__ logits,
    float* __restrict__ out,
    int T)
{
    const int tid = blockIdx.x * blockDim.x + threadIdx.x;
    const int grp = tid >> 4;                       // 16 lanes per token
    const int sub = threadIdx.x & 15;
    const int G   = (gridDim.x * blockDim.x) >> 4;  // total groups

    const int t0 = grp;
    const int t1 = grp + G;

    // Issue BOTH tokens' loads up front (4 dwordx4/thread total = 16 data
    // VGPR); t1's loads stay outstanding through t0's compute.
    float4 A0, A1, B0, B1;
    if (t0 < T) {
        const float4* p0 = reinterpret_cast<const float4*>(logits + (size_t)t0 * NEXPERTS);
        A0 = p0[sub];       // experts [4*sub, 4*sub+4)
        A1 = p0[sub + 16];  // experts [64 + 4*sub, ...)
    }
    if (t1 < T) {
        const float4* p1 = reinterpret_cast<const float4*>(logits + (size_t)t1 * NEXPERTS);
        B0 = p1[sub];
        B1 = p1[sub + 16];
    }

    if (t0 < T) process_token(A0, A1, sub, t0, out, T);
    if (t1 < T) process_token(B0, B1, sub, t1, out, T);
}

extern "C" void kernel_launch(void* const* d_in, const int* in_sizes, int n_in,
                              void* d_out, int out_size, void* d_ws, size_t ws_size,
                              hipStream_t stream) {
    const float* logits = (const float*)d_in[0];
    float* out = (float*)d_out;
    const int T = in_sizes[0] / NEXPERTS;

    // 16 groups... 256/16 = 16 tokens resident x 2 ILP = 32 tokens per block
    const int blocks = (T + 31) / 32;
    sparsemixer_route_kernel<<<blocks, 256, 0, stream>>>(logits, out, T);
}

// Round 13
// 26.996 us; speedup vs baseline: 1.1923x; 1.1923x over previous
//
#include <hip/hip_runtime.h>
#include <math.h>

// SparseMixer MoE routing: T tokens x 128 experts, top-2.
// R13 = pure revert to R10 (best: 27.0us, 5.1 TB/s effective, passed
// absmax 0.002). R11 (8-lane+ILP, 29.8) and R12 (16-lane+ILP, 32.2) both
// regressed: at the 64-VGPR/8-wave occupancy cliff, ANY added per-thread
// state (extra row buffers + live-ranges) costs more than its ILP gains.
// R10's structure: 8 lanes/token, one token/group, no prefetch ->
// minimal regs -> true 8 waves/SIMD; 8192 blocks churn for phase desync.
// Semantics (passed absmax 0.002 in R8/R10/R11/R12):
//   top-2 first-occurrence tie-break == ref {argmax; -inf; argmax}
//   masked <=> x < theta, theta = v>=0 ? 0.98v : v*(1/0.98)  [v>=x always]
//   s1 = sum_{x>=th1} exp(x-v1); s2 = (sum_{x>=th2} exp(x-v1) - 1)*exp(v1-v2)
//   (x[i1]=v1 always passes th2; its exp(0)=1 term removed by the -1)
// Output (floats): out[0..2T) = indices as float; out[2T..4T) = values.

#define NEXPERTS 128
#define INV098 1.0204082f

__global__ __launch_bounds__(256, 8) void sparsemixer_route_kernel(
    const float* __restrict__ logits,
    float* __restrict__ out,
    int T)
{
    const int tid   = blockIdx.x * blockDim.x + threadIdx.x;
    const int token = tid >> 3;            // 8 lanes per token
    const int sub   = threadIdx.x & 7;
    if (token >= T) return;

    const float4* p = reinterpret_cast<const float4*>(logits + (size_t)token * NEXPERTS);
    float4 X[4];
    #pragma unroll
    for (int c = 0; c < 4; ++c) X[c] = p[sub + c * 8];   // one 128B line/group/instr

    // ---- local top-2 over this lane's 16 elements.
    // global e = 4*sub + L with L = 32*c + j; ascending (c,j) scan ==
    // ascending e => first-occurrence tie-break within lane.
    float m1 = -INFINITY, m2 = -INFINITY;
    int   l1 = 0x7fffff, l2 = 0x7fffff;
    #pragma unroll
    for (int c = 0; c < 4; ++c) {
        const float xs[4] = {X[c].x, X[c].y, X[c].z, X[c].w};
        #pragma unroll
        for (int j = 0; j < 4; ++j) {
            const float xv = xs[j];
            const int   L  = 32 * c + j;
            if (xv > m1)      { m2 = m1; l2 = l1; m1 = xv; l1 = L; }
            else if (xv > m2) { m2 = xv; l2 = L; }
        }
    }
    int i1 = 4 * sub + l1;   // global expert indices
    int i2 = 4 * sub + l2;

    // ---- 8-lane joint top-2 butterfly (offsets 4,2,1 stay in the group).
    // Merge keeps {winner.top, best(winner.second, loser.top)}; ties -> smaller idx.
    #pragma unroll
    for (int off = 4; off > 0; off >>= 1) {
        float om1 = __shfl_xor(m1, off); int oi1 = __shfl_xor(i1, off);
        float om2 = __shfl_xor(m2, off); int oi2 = __shfl_xor(i2, off);
        float w1, ws, lt; int wi1, wis, lti;
        if (om1 > m1 || (om1 == m1 && oi1 < i1)) {
            w1 = om1; wi1 = oi1; ws = om2; wis = oi2; lt = m1;  lti = i1;
        } else {
            w1 = m1;  wi1 = i1;  ws = m2;  wis = i2;  lt = om1; lti = oi1;
        }
        if (lt > ws || (lt == ws && lti < wis)) { m2 = lt; i2 = lti; }
        else                                    { m2 = ws; i2 = wis; }
        m1 = w1; i1 = wi1;
    }
    const float v1 = m1, v2 = m2;

    // ---- theta thresholds: kept_s <=> x >= theta_s
    const float th1 = v1 * (v1 >= 0.f ? 0.98f : INV098);
    const float th2 = v2 * (v2 >= 0.f ? 0.98f : INV098);

    // ---- dual masked sums, one exp per element
    float s1 = 0.f, t2 = 0.f;
    #pragma unroll
    for (int c = 0; c < 4; ++c) {
        const float xs[4] = {X[c].x, X[c].y, X[c].z, X[c].w};
        #pragma unroll
        for (int j = 0; j < 4; ++j) {
            const float xv = xs[j];
            const float ev = __expf(xv - v1);
            if (xv >= th1) s1 += ev;
            if (xv >= th2) t2 += ev;   // includes i1's exp(0)=1
        }
    }
    // ---- 8-lane sum butterfly
    #pragma unroll
    for (int off = 4; off > 0; off >>= 1) {
        s1 += __shfl_xor(s1, off);
        t2 += __shfl_xor(t2, off);
    }

    if (sub == 0) {
        const float s2 = (t2 - 1.0f) * __expf(v1 - v2);  // remove i1, rescale
        out[(size_t)token * 2 + 0] = (float)i1;
        out[(size_t)token * 2 + 1] = (float)i2;
        float* vals = out + (size_t)2 * T;
        vals[(size_t)token * 2 + 0] = 1.0f / s1;
        vals[(size_t)token * 2 + 1] = 1.0f / s2;
    }
}

extern "C" void kernel_launch(void* const* d_in, const int* in_sizes, int n_in,
                              void* d_out, int out_size, void* d_ws, size_t ws_size,
                              hipStream_t stream) {
    const float* logits = (const float*)d_in[0];
    float* out = (float*)d_out;
    const int T = in_sizes[0] / NEXPERTS;

    // 32 tokens per 256-thread block (8 lanes each)
    const int blocks = (T + 31) / 32;
    sparsemixer_route_kernel<<<blocks, 256, 0, stream>>>(logits, out, T);
}